// Round 1
// baseline (563.759 us; speedup 1.0000x reference)
//
#include <hip/hip_runtime.h>

// FastMaskedDense1D.update_site  — skinny GEMM  y = A @ K + bias[index]
//   A: (8192 batch, 4800 k)  from cache[:, :299, :] with row 299 <- inputs
//   K: (4800, 16)            strided slice of kernel (row stride 8192 floats)
// Memory-bound: 157 MB A-read @ 6.3 TB/s => ~25 us floor.

#define EXCLUSIVE 1
#define SIZEV     512
#define NF        16
#define NIF       16
#define KROW      (SIZEV * NF)    // kernel row stride in floats (8192)
#define CROW      (SIZEV * NIF)   // cache per-batch stride in floats (8192)
#define MB        16              // batch rows per block
#define KC        256             // k-values per LDS chunk
#define SA        272             // LDS row stride (words): bank = 16*rq + kq -> 2-way max (free)

__device__ __forceinline__ void fma4(float4& a, float s, float4 b) {
    a.x = fmaf(s, b.x, a.x);
    a.y = fmaf(s, b.y, a.y);
    a.z = fmaf(s, b.z, a.z);
    a.w = fmaf(s, b.w, a.w);
}

__device__ __forceinline__ float4 red4(float4 v, int m) {
    v.x += __shfl_xor(v.x, m, 64);
    v.y += __shfl_xor(v.y, m, 64);
    v.z += __shfl_xor(v.z, m, 64);
    v.w += __shfl_xor(v.w, m, 64);
    return v;
}

__global__ __launch_bounds__(256) void fmd_kernel(
    const float* __restrict__ inputs,   // (B, 16)
    const float* __restrict__ cache,    // (B, 512, 16)
    const float* __restrict__ kern,     // (8192, 8192)
    const float* __restrict__ bias,     // (512, 16)
    const int*   __restrict__ idxp,     // scalar
    float*       __restrict__ out)      // (B, 16)
{
    __shared__ float A[2][MB * SA];     // double-buffered A tile, ~34.8 KB

    const int index = *idxp;
    const int jc = index - EXCLUSIVE + 1;        // valid sites; last one sourced from `inputs`
    const int KM = (jc > 0) ? (jc - 1) * NIF : 0; // cache-sourced flattened-k count (mult of 16)
    const int NC = (KM + KC - 1) / KC;           // number of k-chunks

    const int tid  = threadIdx.x;
    const int lane = tid & 63;
    const int w    = tid >> 6;      // wave 0..3
    const int kq   = lane & 15;     // k-slice within chunk
    const int rq   = lane >> 4;     // row group 0..3
    const int rh   = w >> 1;        // row half
    const int fh   = w & 1;         // feature half (8 features)
    const int row0 = blockIdx.x * MB;

    const int lr0 = rh * 8 + rq;    // lane's block-local rows
    const int lr1 = lr0 + 4;

    float4 acc00 = {0,0,0,0}, acc01 = {0,0,0,0};
    float4 acc10 = {0,0,0,0}, acc11 = {0,0,0,0};

    const float4* cvec  = (const float4*)cache;
    const float*  kbase = kern + (size_t)index * NF + (size_t)fh * 8;

    float4 st[4];  // staged A for next chunk (thread stages rows w, w+4, w+8, w+12)

    if (NC > 0) {
        // ---- prolog: stage chunk 0 into buf 0 ----
        #pragma unroll
        for (int p = 0; p < 4; ++p)
            st[p] = cvec[(size_t)(row0 + w + 4*p) * (CROW/4) + lane];
        #pragma unroll
        for (int p = 0; p < 4; ++p)
            *(float4*)&A[0][(w + 4*p) * SA + lane * 4] = st[p];

        for (int c = 0; c < NC; ++c) {
            const int k0 = c * KC;
            // fire next chunk's global loads (fully in-bounds: k0+KC+1023B < row end)
            if (c + 1 < NC) {
                const int k4 = (k0 + KC) >> 2;
                #pragma unroll
                for (int p = 0; p < 4; ++p)
                    st[p] = cvec[(size_t)(row0 + w + 4*p) * (CROW/4) + k4 + lane];
            }
            __syncthreads();   // prev ds_writes visible; separates readers from upcoming writes

            const int buf  = c & 1;
            const int kend = min(KC, KM - k0);   // multiple of 16
            const int nt   = kend >> 4;
            const float* Ab = &A[buf][0];

            #pragma unroll 4
            for (int t = 0; t < nt; ++t) {
                const int kk = kq + 16 * t;
                float a0 = Ab[lr0 * SA + kk];
                float a1 = Ab[lr1 * SA + kk];
                const float* kp = kbase + (size_t)(k0 + kk) * KROW;
                float4 kv0 = *(const float4*)kp;
                float4 kv1 = *(const float4*)(kp + 4);
                fma4(acc00, a0, kv0); fma4(acc01, a0, kv1);
                fma4(acc10, a1, kv0); fma4(acc11, a1, kv1);
            }

            if (c + 1 < NC) {
                const int b2 = (c + 1) & 1;
                #pragma unroll
                for (int p = 0; p < 4; ++p)
                    *(float4*)&A[b2][(w + 4*p) * SA + lane * 4] = st[p];
            }
        }
    }

    // ---- epilogue: row j = jc-1 comes from `inputs` (the scattered site) ----
    if (jc > 0) {
        const float* kp = kbase + (size_t)((jc - 1) * NIF + kq) * KROW;
        float4 kv0 = *(const float4*)kp;
        float4 kv1 = *(const float4*)(kp + 4);
        float in0 = inputs[(size_t)(row0 + lr0) * NIF + kq];
        float in1 = inputs[(size_t)(row0 + lr1) * NIF + kq];
        fma4(acc00, in0, kv0); fma4(acc01, in0, kv1);
        fma4(acc10, in1, kv0); fma4(acc11, in1, kv1);
    }

    // ---- butterfly reduce over the 16 kq lanes (xor bits 0..3) ----
    #pragma unroll
    for (int m = 1; m <= 8; m <<= 1) {
        acc00 = red4(acc00, m); acc01 = red4(acc01, m);
        acc10 = red4(acc10, m); acc11 = red4(acc11, m);
    }

    // ---- write: lanes kq<4 each store one float4 (+bias) ----
    if (kq < 4) {
        const int rp = kq >> 1;   // which of the lane's two rows
        const int qp = kq & 1;    // which feature quad within the half
        float4 v = (rp == 0) ? (qp == 0 ? acc00 : acc01)
                             : (qp == 0 ? acc10 : acc11);
        const int row  = row0 + lr0 + 4 * rp;
        const int fcol = fh * 8 + qp * 4;
        float4 b4 = *(const float4*)&bias[(size_t)index * NF + fcol];
        v.x += b4.x; v.y += b4.y; v.z += b4.z; v.w += b4.w;
        *(float4*)&out[(size_t)row * NF + fcol] = v;
    }
}

extern "C" void kernel_launch(void* const* d_in, const int* in_sizes, int n_in,
                              void* d_out, int out_size, void* d_ws, size_t ws_size,
                              hipStream_t stream) {
    const float* inputs = (const float*)d_in[0];
    const float* cache  = (const float*)d_in[1];
    const float* kern   = (const float*)d_in[2];
    const float* bias   = (const float*)d_in[3];
    const int*   idxp   = (const int*)d_in[4];
    float*       out    = (float*)d_out;

    const int batch = in_sizes[0] / NIF;       // 8192
    const int grid  = batch / MB;              // 512 blocks (2/CU)

    fmd_kernel<<<grid, 256, 0, stream>>>(inputs, cache, kern, bias, idxp, out);
}